// Round 4
// baseline (172.244 us; speedup 1.0000x reference)
//
#include <hip/hip_runtime.h>
#include <hip/hip_bf16.h>

// Problem constants (fixed by the reference file).
#define Bq  4
#define Cq  64
#define Hq  256
#define Wq  256
#define Nq  300000
#define Kq  16
#define NVq 6890
#define TOTAL (Bq * Nq)

// Binning: 16x16-pixel tiles -> 16x16 tiles/image x 4 batches = 1024 bins.
#define NBINS 1024

// Workspace layout (bytes).
#define OFF_FMTB 0
#define SZ_FMTB  ((size_t)Bq * Hq * Wq * Cq * 2)            // 33,554,432
#define OFF_HIST (SZ_FMTB)                                   // 4096
#define OFF_OFFS (OFF_HIST + 4096)
#define OFF_CURS (OFF_OFFS + 4096)
#define OFF_TID  (OFF_CURS + 4096)                           // ushort per g
#define SZ_TID   ((size_t)TOTAL * 2)                         // 2,400,000
#define OFF_SORT (OFF_TID + SZ_TID)                          // uint per pos
#define SZ_SORT  ((size_t)TOTAL * 4)                         // 4,800,000
#define WS_NEED  (OFF_SORT + SZ_SORT)                        // ~40.8 MB

typedef float          f32x4 __attribute__((ext_vector_type(4)));
typedef unsigned short u16x8 __attribute__((ext_vector_type(8)));

__device__ __forceinline__ float bf2f(unsigned short u) {
    return __uint_as_float(((unsigned)u) << 16);
}
__device__ __forceinline__ unsigned short f2bf(float x) {
    __hip_bfloat16 v = __float2bfloat16(x);   // RNE
    return *reinterpret_cast<unsigned short*>(&v);
}

// Shared per-n scalar pipeline: from flat g -> sampling params.
struct SampleParams {
    float px, py;   // pixel coords
    int   b;
};
__device__ __forceinline__ SampleParams compute_center(
    int g, const float* __restrict__ verts, const float* __restrict__ bary,
    const int* __restrict__ parents)
{
    const int b = g / Nq;
    const int n = g - b * Nq;

    const int k = n & (Kq - 1);
    const float w0 = bary[k * 3 + 0];
    const float w1 = bary[k * 3 + 1];
    const float w2 = bary[k * 3 + 2];

    const int p0 = parents[n * 3 + 0];
    const int p1 = parents[n * 3 + 1];
    const int p2 = parents[n * 3 + 2];

    const float* vb = verts + (size_t)b * NVq * 2;
    const float cx = w0 * vb[p0 * 2 + 0] + w1 * vb[p1 * 2 + 0] + w2 * vb[p2 * 2 + 0];
    const float cy = w0 * vb[p0 * 2 + 1] + w1 * vb[p1 * 2 + 1] + w2 * vb[p2 * 2 + 1];

    // replicate reference's normalize -> denormalize round-trip exactly
    const float gx = cx / (float)(Wq - 1) * 2.0f - 1.0f;
    const float gy = cy / (float)(Hq - 1) * 2.0f - 1.0f;

    SampleParams sp;
    sp.px = (gx + 1.0f) * 0.5f * (float)(Wq - 1);
    sp.py = (gy + 1.0f) * 0.5f * (float)(Hq - 1);
    sp.b  = b;
    return sp;
}

// ---------------------------------------------------------------------------
// K1: transpose + quantize (B,C,H,W) fp32 -> (B,H,W,C) bf16.
// ---------------------------------------------------------------------------
__global__ __launch_bounds__(256) void transpose_kernel(
    const float* __restrict__ fm, unsigned short* __restrict__ fmtb)
{
    __shared__ float tile[64][65];
    const int blk = blockIdx.x;                 // 0 .. B*(HW/64)-1
    const int b   = blk / (Hq * Wq / 64);
    const int hw0 = (blk % (Hq * Wq / 64)) * 64;
    const int t   = threadIdx.x;
    const int tx  = t & 63;
    const int ty  = t >> 6;

    const float* src = fm + (size_t)b * Cq * (Hq * Wq);
    #pragma unroll
    for (int c = ty; c < 64; c += 4) {
        tile[c][tx] = __builtin_nontemporal_load(
            src + (size_t)c * (Hq * Wq) + hw0 + tx);           // coalesced
    }
    __syncthreads();

    // store: 8 pixels per iter; 32 lanes/pixel, each lane packs 2 bf16 ch.
    unsigned int* dstu = (unsigned int*)(fmtb + ((size_t)b * (Hq * Wq) + hw0) * Cq);
    const int c2 = (t & 31) * 2;
    #pragma unroll
    for (int r0 = 0; r0 < 64; r0 += 8) {
        const int p = r0 + (t >> 5);
        const unsigned int lo = f2bf(tile[c2][p]);
        const unsigned int hi = f2bf(tile[c2 + 1][p]);
        dstu[p * 32 + (c2 >> 1)] = lo | (hi << 16);            // 256B/wave
    }
}

// ---------------------------------------------------------------------------
// K2: per-n bin id (16x16 tile) + LDS-aggregated global histogram.
// ---------------------------------------------------------------------------
__global__ __launch_bounds__(256) void bin_kernel(
    const float* __restrict__ verts, const float* __restrict__ bary,
    const int* __restrict__ parents,
    unsigned short* __restrict__ tid, unsigned int* __restrict__ hist)
{
    __shared__ unsigned int h[NBINS];
    const int t = threadIdx.x;
    for (int i = t; i < NBINS; i += 256) h[i] = 0;
    __syncthreads();

    const int base = blockIdx.x * 4096;
    #pragma unroll
    for (int i = 0; i < 16; ++i) {
        const int g = base + i * 256 + t;
        if (g < TOTAL) {
            SampleParams sp = compute_center(g, verts, bary, parents);
            int x0 = (int)floorf(sp.px);
            int y0 = (int)floorf(sp.py);
            x0 = min(max(x0, 0), Wq - 1);
            y0 = min(max(y0, 0), Hq - 1);
            const int bin = sp.b * 256 + (y0 >> 4) * 16 + (x0 >> 4);
            tid[g] = (unsigned short)bin;
            atomicAdd(&h[bin], 1u);
        }
    }
    __syncthreads();
    for (int i = t; i < NBINS; i += 256) {
        const unsigned int c = h[i];
        if (c) atomicAdd(&hist[i], c);
    }
}

// ---------------------------------------------------------------------------
// K3: exclusive scan of 1024-bin histogram (one block), writes offs + cursor.
// ---------------------------------------------------------------------------
__global__ __launch_bounds__(1024) void scan_kernel(
    const unsigned int* __restrict__ hist,
    unsigned int* __restrict__ offs, unsigned int* __restrict__ curs)
{
    __shared__ unsigned int a[NBINS];
    const int t = threadIdx.x;
    const unsigned int v0 = hist[t];
    a[t] = v0;
    __syncthreads();
    #pragma unroll
    for (int s = 1; s < NBINS; s <<= 1) {
        const unsigned int x = (t >= s) ? a[t - s] : 0u;
        __syncthreads();
        a[t] += x;
        __syncthreads();
    }
    const unsigned int excl = a[t] - v0;
    offs[t] = excl;
    curs[t] = excl;
}

// ---------------------------------------------------------------------------
// K4: scatter n-indices into bin-sorted order (block-aggregated reservation).
// ---------------------------------------------------------------------------
__global__ __launch_bounds__(256) void scatter_kernel(
    const unsigned short* __restrict__ tid,
    unsigned int* __restrict__ curs, unsigned int* __restrict__ sorted)
{
    __shared__ unsigned int cnt[NBINS];
    __shared__ unsigned int bas[NBINS];
    const int t = threadIdx.x;
    for (int i = t; i < NBINS; i += 256) cnt[i] = 0;
    __syncthreads();

    const int base = blockIdx.x * 4096;
    unsigned short myb[16];
    #pragma unroll
    for (int i = 0; i < 16; ++i) {
        const int g = base + i * 256 + t;
        if (g < TOTAL) {
            myb[i] = tid[g];
            atomicAdd(&cnt[myb[i]], 1u);
        }
    }
    __syncthreads();
    for (int i = t; i < NBINS; i += 256) {
        const unsigned int c = cnt[i];
        bas[i] = c ? atomicAdd(&curs[i], c) : 0u;
        cnt[i] = 0;
    }
    __syncthreads();
    #pragma unroll
    for (int i = 0; i < 16; ++i) {
        const int g = base + i * 256 + t;
        if (g < TOTAL) {
            const unsigned int r = atomicAdd(&cnt[myb[i]], 1u);
            sorted[bas[myb[i]] + r] = (unsigned int)g;
        }
    }
}

// ---------------------------------------------------------------------------
// K5: gather in bin-sorted order. Phase A per thread -> LDS params;
// Phase B: 8 lanes/n x 8 bf16 channels (16B loads), L2-resident gathers.
// ---------------------------------------------------------------------------
__global__ __launch_bounds__(256) void sample_sorted_kernel(
    const unsigned short* __restrict__ fmtb,  // (B,H,W,C) bf16
    const float* __restrict__ verts,
    const float* __restrict__ bary,
    const int*   __restrict__ parents,
    const unsigned int* __restrict__ sorted,
    float* __restrict__ out)
{
    __shared__ int          s_ofs[256][4];
    __shared__ float        s_wts[256][4];
    __shared__ unsigned int s_n[256];

    const int t     = threadIdx.x;
    const int gbase = blockIdx.x * 256;

    // ---------------- Phase A ----------------
    if (gbase + t < TOTAL) {
        const int gs = (int)sorted[gbase + t];   // original (b,n) flat index
        s_n[t] = (unsigned int)gs;

        SampleParams sp = compute_center(gs, verts, bary, parents);
        const float x0f = floorf(sp.px);
        const float y0f = floorf(sp.py);
        const float fx = sp.px - x0f;
        const float fy = sp.py - y0f;

        const int ix0 = (int)x0f, iy0 = (int)y0f;
        const int ix1 = ix0 + 1,  iy1 = iy0 + 1;

        const float vx0 = (x0f >= 0.0f        && x0f <= (float)(Wq - 1)) ? 1.0f : 0.0f;
        const float vx1 = (x0f + 1.0f >= 0.0f && x0f + 1.0f <= (float)(Wq - 1)) ? 1.0f : 0.0f;
        const float vy0 = (y0f >= 0.0f        && y0f <= (float)(Hq - 1)) ? 1.0f : 0.0f;
        const float vy1 = (y0f + 1.0f >= 0.0f && y0f + 1.0f <= (float)(Hq - 1)) ? 1.0f : 0.0f;

        const int cx0 = min(max(ix0, 0), Wq - 1);
        const int cx1 = min(max(ix1, 0), Wq - 1);
        const int cy0 = min(max(iy0, 0), Hq - 1);
        const int cy1 = min(max(iy1, 0), Hq - 1);

        const int bb = sp.b * (Hq * Wq * Cq);
        s_ofs[t][0] = bb + (cy0 * Wq + cx0) * Cq;
        s_ofs[t][1] = bb + (cy0 * Wq + cx1) * Cq;
        s_ofs[t][2] = bb + (cy1 * Wq + cx0) * Cq;
        s_ofs[t][3] = bb + (cy1 * Wq + cx1) * Cq;

        s_wts[t][0] = (1.0f - fx) * (1.0f - fy) * vx0 * vy0;
        s_wts[t][1] = fx          * (1.0f - fy) * vx1 * vy0;
        s_wts[t][2] = (1.0f - fx) * fy          * vx0 * vy1;
        s_wts[t][3] = fx          * fy          * vx1 * vy1;
    } else {
        s_n[t] = 0;
        s_ofs[t][0] = s_ofs[t][1] = s_ofs[t][2] = s_ofs[t][3] = 0;
        s_wts[t][0] = s_wts[t][1] = s_wts[t][2] = s_wts[t][3] = 0.0f;
    }
    __syncthreads();

    // ---------------- Phase B ----------------
    const int wv   = t >> 6;
    const int lane = t & 63;
    const int q    = lane >> 3;          // 0..7 -> which n in group
    const int c8   = (lane & 7) * 8;     // 8 channels per lane

    #pragma unroll 2
    for (int i = 0; i < 8; ++i) {
        const int li  = wv * 64 + i * 8 + q;
        if (gbase + li >= TOTAL) continue;

        const int4   o = *(const int4*)  s_ofs[li];
        const float4 w = *(const float4*)s_wts[li];

        const u16x8 a0 = *(const u16x8*)(fmtb + o.x + c8);
        const u16x8 a1 = *(const u16x8*)(fmtb + o.y + c8);
        const u16x8 a2 = *(const u16x8*)(fmtb + o.z + c8);
        const u16x8 a3 = *(const u16x8*)(fmtb + o.w + c8);

        f32x4 lo, hi;
        #pragma unroll
        for (int j = 0; j < 4; ++j) {
            lo[j] = bf2f(a0[j]) * w.x + bf2f(a1[j]) * w.y
                  + bf2f(a2[j]) * w.z + bf2f(a3[j]) * w.w;
        }
        #pragma unroll
        for (int j = 0; j < 4; ++j) {
            hi[j] = bf2f(a0[4 + j]) * w.x + bf2f(a1[4 + j]) * w.y
                  + bf2f(a2[4 + j]) * w.z + bf2f(a3[4 + j]) * w.w;
        }

        float* op = out + (size_t)s_n[li] * Cq + c8;
        *(f32x4*)op       = lo;
        *(f32x4*)(op + 4) = hi;
    }
}

// ---------------------------------------------------------------------------
// Fallback: R3-style linear-order sample (ws fits map only).
// ---------------------------------------------------------------------------
__global__ __launch_bounds__(256) void sample_kernel(
    const unsigned short* __restrict__ fmtb,
    const float* __restrict__ verts,
    const float* __restrict__ bary,
    const int*   __restrict__ parents,
    float* __restrict__ out)
{
    __shared__ int   s_ofs[256][4];
    __shared__ float s_wts[256][4];

    const int t     = threadIdx.x;
    const int gbase = blockIdx.x * 256;
    const int g     = gbase + t;

    if (g < TOTAL) {
        SampleParams sp = compute_center(g, verts, bary, parents);
        const float x0f = floorf(sp.px);
        const float y0f = floorf(sp.py);
        const float fx = sp.px - x0f;
        const float fy = sp.py - y0f;

        const int ix0 = (int)x0f, iy0 = (int)y0f;
        const int ix1 = ix0 + 1,  iy1 = iy0 + 1;

        const float vx0 = (x0f >= 0.0f        && x0f <= (float)(Wq - 1)) ? 1.0f : 0.0f;
        const float vx1 = (x0f + 1.0f >= 0.0f && x0f + 1.0f <= (float)(Wq - 1)) ? 1.0f : 0.0f;
        const float vy0 = (y0f >= 0.0f        && y0f <= (float)(Hq - 1)) ? 1.0f : 0.0f;
        const float vy1 = (y0f + 1.0f >= 0.0f && y0f + 1.0f <= (float)(Hq - 1)) ? 1.0f : 0.0f;

        const int cx0 = min(max(ix0, 0), Wq - 1);
        const int cx1 = min(max(ix1, 0), Wq - 1);
        const int cy0 = min(max(iy0, 0), Hq - 1);
        const int cy1 = min(max(iy1, 0), Hq - 1);

        const int bb = sp.b * (Hq * Wq * Cq);
        s_ofs[t][0] = bb + (cy0 * Wq + cx0) * Cq;
        s_ofs[t][1] = bb + (cy0 * Wq + cx1) * Cq;
        s_ofs[t][2] = bb + (cy1 * Wq + cx0) * Cq;
        s_ofs[t][3] = bb + (cy1 * Wq + cx1) * Cq;

        s_wts[t][0] = (1.0f - fx) * (1.0f - fy) * vx0 * vy0;
        s_wts[t][1] = fx          * (1.0f - fy) * vx1 * vy0;
        s_wts[t][2] = (1.0f - fx) * fy          * vx0 * vy1;
        s_wts[t][3] = fx          * fy          * vx1 * vy1;
    } else {
        s_ofs[t][0] = s_ofs[t][1] = s_ofs[t][2] = s_ofs[t][3] = 0;
        s_wts[t][0] = s_wts[t][1] = s_wts[t][2] = s_wts[t][3] = 0.0f;
    }
    __syncthreads();

    const int wv   = t >> 6;
    const int lane = t & 63;
    const int q    = lane >> 3;
    const int c8   = (lane & 7) * 8;

    #pragma unroll 2
    for (int i = 0; i < 8; ++i) {
        const int li = wv * 64 + i * 8 + q;
        const int gg = gbase + li;
        if (gg >= TOTAL) continue;

        const int4   o = *(const int4*)  s_ofs[li];
        const float4 w = *(const float4*)s_wts[li];

        const u16x8 a0 = *(const u16x8*)(fmtb + o.x + c8);
        const u16x8 a1 = *(const u16x8*)(fmtb + o.y + c8);
        const u16x8 a2 = *(const u16x8*)(fmtb + o.z + c8);
        const u16x8 a3 = *(const u16x8*)(fmtb + o.w + c8);

        f32x4 lo, hi;
        #pragma unroll
        for (int j = 0; j < 4; ++j) {
            lo[j] = bf2f(a0[j]) * w.x + bf2f(a1[j]) * w.y
                  + bf2f(a2[j]) * w.z + bf2f(a3[j]) * w.w;
        }
        #pragma unroll
        for (int j = 0; j < 4; ++j) {
            hi[j] = bf2f(a0[4 + j]) * w.x + bf2f(a1[4 + j]) * w.y
                  + bf2f(a2[4 + j]) * w.z + bf2f(a3[4 + j]) * w.w;
        }

        float* op = out + (size_t)gg * Cq + c8;
        __builtin_nontemporal_store(lo, (f32x4*)op);
        __builtin_nontemporal_store(hi, (f32x4*)(op + 4));
    }
}

extern "C" void kernel_launch(void* const* d_in, const int* in_sizes, int n_in,
                              void* d_out, int out_size, void* d_ws, size_t ws_size,
                              hipStream_t stream)
{
    const float* fm      = (const float*)d_in[0];   // (B,C,H,W) fp32
    const float* verts   = (const float*)d_in[1];   // (B,NV,2) fp32
    const float* bary    = (const float*)d_in[2];   // (K,3) fp32
    const int*   parents = (const int*)  d_in[3];   // (N,3) int32
    float* out = (float*)d_out;                     // (B,N,C) fp32

    char* ws = (char*)d_ws;
    unsigned short* fmtb   = (unsigned short*)(ws + OFF_FMTB);
    unsigned int*   hist   = (unsigned int*)  (ws + OFF_HIST);
    unsigned int*   offs   = (unsigned int*)  (ws + OFF_OFFS);
    unsigned int*   curs   = (unsigned int*)  (ws + OFF_CURS);
    unsigned short* tid    = (unsigned short*)(ws + OFF_TID);
    unsigned int*   sorted = (unsigned int*)  (ws + OFF_SORT);

    const int nblk_n   = (TOTAL + 4095) / 4096;   // 293 (bin/scatter)
    const int nblk_s   = (TOTAL + 255) / 256;     // 4688 (sample)
    const int nblk_t   = Bq * (Hq * Wq / 64);     // 4096 (transpose)

    if (ws_size >= WS_NEED) {
        hipMemsetAsync(hist, 0, NBINS * sizeof(unsigned int), stream);
        bin_kernel    <<<nblk_n, 256,  0, stream>>>(verts, bary, parents, tid, hist);
        scan_kernel   <<<1,      1024, 0, stream>>>(hist, offs, curs);
        scatter_kernel<<<nblk_n, 256,  0, stream>>>(tid, curs, sorted);
        transpose_kernel<<<nblk_t, 256, 0, stream>>>(fm, fmtb);
        sample_sorted_kernel<<<nblk_s, 256, 0, stream>>>(fmtb, verts, bary,
                                                         parents, sorted, out);
    } else if (ws_size >= SZ_FMTB) {
        transpose_kernel<<<nblk_t, 256, 0, stream>>>(fm, fmtb);
        sample_kernel<<<nblk_s, 256, 0, stream>>>(fmtb, verts, bary, parents, out);
    }
}

// Round 5
// 132.510 us; speedup vs baseline: 1.2999x; 1.2999x over previous
//
#include <hip/hip_runtime.h>
#include <hip/hip_bf16.h>

// Problem constants (fixed by the reference file).
#define Bq  4
#define Cq  64
#define Hq  256
#define Wq  256
#define Nq  300000
#define Kq  16
#define NVq 6890
#define TOTAL (Bq * Nq)

#define SZ_FMTB ((size_t)Bq * Hq * Wq * Cq * 2)   // 32 MiB bf16 map

typedef float          f32x4 __attribute__((ext_vector_type(4)));
typedef unsigned short u16x8 __attribute__((ext_vector_type(8)));

__device__ __forceinline__ float bf2f(unsigned short u) {
    return __uint_as_float(((unsigned)u) << 16);
}
__device__ __forceinline__ unsigned short f2bf(float x) {
    __hip_bfloat16 v = __float2bfloat16(x);   // RNE
    return *reinterpret_cast<unsigned short*>(&v);
}

// Shared per-n scalar pipeline: flat g -> pixel-space sample point.
struct SampleParams { float px, py; int b; };
__device__ __forceinline__ SampleParams compute_center(
    int g, const float* __restrict__ verts, const float* __restrict__ bary,
    const int* __restrict__ parents)
{
    const int b = g / Nq;
    const int n = g - b * Nq;

    const int k = n & (Kq - 1);
    const float w0 = bary[k * 3 + 0];
    const float w1 = bary[k * 3 + 1];
    const float w2 = bary[k * 3 + 2];

    const int p0 = parents[n * 3 + 0];
    const int p1 = parents[n * 3 + 1];
    const int p2 = parents[n * 3 + 2];

    const float* vb = verts + (size_t)b * NVq * 2;
    const float cx = w0 * vb[p0 * 2 + 0] + w1 * vb[p1 * 2 + 0] + w2 * vb[p2 * 2 + 0];
    const float cy = w0 * vb[p0 * 2 + 1] + w1 * vb[p1 * 2 + 1] + w2 * vb[p2 * 2 + 1];

    // replicate reference's normalize -> denormalize round-trip exactly
    const float gx = cx / (float)(Wq - 1) * 2.0f - 1.0f;
    const float gy = cy / (float)(Hq - 1) * 2.0f - 1.0f;

    SampleParams sp;
    sp.px = (gx + 1.0f) * 0.5f * (float)(Wq - 1);
    sp.py = (gy + 1.0f) * 0.5f * (float)(Hq - 1);
    sp.b  = b;
    return sp;
}

// ---------------------------------------------------------------------------
// K1: transpose + quantize (B,C,H,W) fp32 -> (B,H,W,C) bf16.
// fm is read-once -> NT loads; fmtb we WANT resident in L2/L3 -> normal stores.
// ---------------------------------------------------------------------------
__global__ __launch_bounds__(256) void transpose_kernel(
    const float* __restrict__ fm, unsigned short* __restrict__ fmtb)
{
    __shared__ float tile[64][65];
    const int blk = blockIdx.x;                 // 0 .. B*(HW/64)-1
    const int b   = blk / (Hq * Wq / 64);
    const int hw0 = (blk % (Hq * Wq / 64)) * 64;
    const int t   = threadIdx.x;
    const int tx  = t & 63;
    const int ty  = t >> 6;

    const float* src = fm + (size_t)b * Cq * (Hq * Wq);
    #pragma unroll
    for (int c = ty; c < 64; c += 4) {
        tile[c][tx] = __builtin_nontemporal_load(
            src + (size_t)c * (Hq * Wq) + hw0 + tx);           // coalesced
    }
    __syncthreads();

    // store: 8 pixels per iter; 32 lanes/pixel, each lane packs 2 bf16 ch.
    unsigned int* dstu = (unsigned int*)(fmtb + ((size_t)b * (Hq * Wq) + hw0) * Cq);
    const int c2 = (t & 31) * 2;
    #pragma unroll
    for (int r0 = 0; r0 < 64; r0 += 8) {
        const int p = r0 + (t >> 5);
        const unsigned int lo = f2bf(tile[c2][p]);
        const unsigned int hi = f2bf(tile[c2 + 1][p]);
        dstu[p * 32 + (c2 >> 1)] = lo | (hi << 16);            // 256B/wave
    }
}

// ---------------------------------------------------------------------------
// K2 (fused two-phase): Phase A per-thread params -> LDS;
// Phase B: 8 lanes/n x 8 bf16 channels (16B loads). PLAIN stores this round
// (A/B vs R3's nontemporal: fillBuffer evidence says plain streaming stores
// sustain ~6.8 TB/s).
// ---------------------------------------------------------------------------
__global__ __launch_bounds__(256) void sample_kernel(
    const unsigned short* __restrict__ fmtb,  // (B,H,W,C) bf16
    const float* __restrict__ verts,
    const float* __restrict__ bary,
    const int*   __restrict__ parents,
    float* __restrict__ out)                  // (B,N,C) fp32
{
    __shared__ int   s_ofs[256][4];
    __shared__ float s_wts[256][4];

    const int t     = threadIdx.x;
    const int gbase = blockIdx.x * 256;
    const int g     = gbase + t;

    // ---------------- Phase A ----------------
    if (g < TOTAL) {
        SampleParams sp = compute_center(g, verts, bary, parents);
        const float x0f = floorf(sp.px);
        const float y0f = floorf(sp.py);
        const float fx = sp.px - x0f;
        const float fy = sp.py - y0f;

        const int ix0 = (int)x0f, iy0 = (int)y0f;
        const int ix1 = ix0 + 1,  iy1 = iy0 + 1;

        const float vx0 = (x0f >= 0.0f        && x0f <= (float)(Wq - 1)) ? 1.0f : 0.0f;
        const float vx1 = (x0f + 1.0f >= 0.0f && x0f + 1.0f <= (float)(Wq - 1)) ? 1.0f : 0.0f;
        const float vy0 = (y0f >= 0.0f        && y0f <= (float)(Hq - 1)) ? 1.0f : 0.0f;
        const float vy1 = (y0f + 1.0f >= 0.0f && y0f + 1.0f <= (float)(Hq - 1)) ? 1.0f : 0.0f;

        const int cx0 = min(max(ix0, 0), Wq - 1);
        const int cx1 = min(max(ix1, 0), Wq - 1);
        const int cy0 = min(max(iy0, 0), Hq - 1);
        const int cy1 = min(max(iy1, 0), Hq - 1);

        const int bb = sp.b * (Hq * Wq * Cq);
        s_ofs[t][0] = bb + (cy0 * Wq + cx0) * Cq;
        s_ofs[t][1] = bb + (cy0 * Wq + cx1) * Cq;
        s_ofs[t][2] = bb + (cy1 * Wq + cx0) * Cq;
        s_ofs[t][3] = bb + (cy1 * Wq + cx1) * Cq;

        s_wts[t][0] = (1.0f - fx) * (1.0f - fy) * vx0 * vy0;
        s_wts[t][1] = fx          * (1.0f - fy) * vx1 * vy0;
        s_wts[t][2] = (1.0f - fx) * fy          * vx0 * vy1;
        s_wts[t][3] = fx          * fy          * vx1 * vy1;
    } else {
        s_ofs[t][0] = s_ofs[t][1] = s_ofs[t][2] = s_ofs[t][3] = 0;
        s_wts[t][0] = s_wts[t][1] = s_wts[t][2] = s_wts[t][3] = 0.0f;
    }
    __syncthreads();

    // ---------------- Phase B ----------------
    const int wv   = t >> 6;
    const int lane = t & 63;
    const int q    = lane >> 3;          // 0..7 -> which n in group of 8
    const int c8   = (lane & 7) * 8;     // 8 channels per lane

    const bool full = (gbase + 256 <= TOTAL);   // uniform: branch-free hot path

    #pragma unroll 2
    for (int i = 0; i < 8; ++i) {
        const int li = wv * 64 + i * 8 + q;
        if (!full && gbase + li >= TOTAL) continue;

        const int4   o = *(const int4*)  s_ofs[li];
        const float4 w = *(const float4*)s_wts[li];

        const u16x8 a0 = *(const u16x8*)(fmtb + o.x + c8);
        const u16x8 a1 = *(const u16x8*)(fmtb + o.y + c8);
        const u16x8 a2 = *(const u16x8*)(fmtb + o.z + c8);
        const u16x8 a3 = *(const u16x8*)(fmtb + o.w + c8);

        f32x4 lo, hi;
        #pragma unroll
        for (int j = 0; j < 4; ++j) {
            lo[j] = bf2f(a0[j]) * w.x + bf2f(a1[j]) * w.y
                  + bf2f(a2[j]) * w.z + bf2f(a3[j]) * w.w;
        }
        #pragma unroll
        for (int j = 0; j < 4; ++j) {
            hi[j] = bf2f(a0[4 + j]) * w.x + bf2f(a1[4 + j]) * w.y
                  + bf2f(a2[4 + j]) * w.z + bf2f(a3[4 + j]) * w.w;
        }

        float* op = out + (size_t)(gbase + li) * Cq + c8;
        *(f32x4*)op       = lo;        // plain stores (A/B vs NT)
        *(f32x4*)(op + 4) = hi;
    }
}

// ---------------------------------------------------------------------------
// Fallback (workspace too small): sample directly from (B,C,H,W), fp32 exact.
// ---------------------------------------------------------------------------
__global__ __launch_bounds__(256) void sample_direct_kernel(
    const float* __restrict__ fm,
    const float* __restrict__ verts,
    const float* __restrict__ bary,
    const int*   __restrict__ parents,
    float* __restrict__ out)
{
    const int g = blockIdx.x * 4 + (threadIdx.x >> 6);
    if (g >= TOTAL) return;
    const int lane = threadIdx.x & 63;

    SampleParams sp = compute_center(g, verts, bary, parents);
    const float x0f = floorf(sp.px);
    const float y0f = floorf(sp.py);
    const float fx = sp.px - x0f;
    const float fy = sp.py - y0f;

    const int ix0 = (int)x0f, iy0 = (int)y0f;
    const int ix1 = ix0 + 1,  iy1 = iy0 + 1;

    const float vx0 = (x0f >= 0.0f        && x0f <= (float)(Wq - 1)) ? 1.0f : 0.0f;
    const float vx1 = (x0f + 1.0f >= 0.0f && x0f + 1.0f <= (float)(Wq - 1)) ? 1.0f : 0.0f;
    const float vy0 = (y0f >= 0.0f        && y0f <= (float)(Hq - 1)) ? 1.0f : 0.0f;
    const float vy1 = (y0f + 1.0f >= 0.0f && y0f + 1.0f <= (float)(Hq - 1)) ? 1.0f : 0.0f;

    const int cx0 = min(max(ix0, 0), Wq - 1);
    const int cx1 = min(max(ix1, 0), Wq - 1);
    const int cy0 = min(max(iy0, 0), Hq - 1);
    const int cy1 = min(max(iy1, 0), Hq - 1);

    const float* base = fm + ((size_t)sp.b * Cq + lane) * (Hq * Wq);
    const float v00 = base[cy0 * Wq + cx0] * (vx0 * vy0);
    const float v01 = base[cy0 * Wq + cx1] * (vx1 * vy0);
    const float v10 = base[cy1 * Wq + cx0] * (vx0 * vy1);
    const float v11 = base[cy1 * Wq + cx1] * (vx1 * vy1);

    const float res = (v00 * (1.0f - fx) + v01 * fx) * (1.0f - fy)
                    + (v10 * (1.0f - fx) + v11 * fx) * fy;

    out[(size_t)g * Cq + lane] = res;
}

extern "C" void kernel_launch(void* const* d_in, const int* in_sizes, int n_in,
                              void* d_out, int out_size, void* d_ws, size_t ws_size,
                              hipStream_t stream)
{
    const float* fm      = (const float*)d_in[0];   // (B,C,H,W) fp32
    const float* verts   = (const float*)d_in[1];   // (B,NV,2) fp32
    const float* bary    = (const float*)d_in[2];   // (K,3) fp32
    const int*   parents = (const int*)  d_in[3];   // (N,3) int32
    float* out = (float*)d_out;                     // (B,N,C) fp32

    const int nblk_s = (TOTAL + 255) / 256;     // 4688
    const int nblk_t = Bq * (Hq * Wq / 64);     // 4096

    if (ws_size >= SZ_FMTB) {
        unsigned short* fmtb = (unsigned short*)d_ws;
        transpose_kernel<<<nblk_t, 256, 0, stream>>>(fm, fmtb);
        sample_kernel<<<nblk_s, 256, 0, stream>>>(fmtb, verts, bary, parents, out);
    } else {
        sample_direct_kernel<<<(TOTAL + 3) / 4, 256, 0, stream>>>(fm, verts, bary, parents, out);
    }
}

// Round 6
// 127.031 us; speedup vs baseline: 1.3559x; 1.0431x over previous
//
#include <hip/hip_runtime.h>
#include <hip/hip_bf16.h>

// Problem constants (fixed by the reference file).
#define Bq  4
#define Cq  64
#define Hq  256
#define Wq  256
#define Nq  300000
#define Kq  16
#define NVq 6890
#define TOTAL (Bq * Nq)

#define SZ_FMTB ((size_t)Bq * Hq * Wq * Cq * 2)   // 32 MiB bf16 map

typedef float          f32x4 __attribute__((ext_vector_type(4)));
typedef unsigned short u16x8 __attribute__((ext_vector_type(8)));

__device__ __forceinline__ float bf2f(unsigned short u) {
    return __uint_as_float(((unsigned)u) << 16);
}
__device__ __forceinline__ unsigned short f2bf(float x) {
    __hip_bfloat16 v = __float2bfloat16(x);   // RNE
    return *reinterpret_cast<unsigned short*>(&v);
}

// Shared per-n scalar pipeline: flat g -> pixel-space sample point.
struct SampleParams { float px, py; int b; };
__device__ __forceinline__ SampleParams compute_center(
    int g, const float* __restrict__ verts, const float* __restrict__ bary,
    const int* __restrict__ parents)
{
    const int b = g / Nq;
    const int n = g - b * Nq;

    const int k = n & (Kq - 1);
    const float w0 = bary[k * 3 + 0];
    const float w1 = bary[k * 3 + 1];
    const float w2 = bary[k * 3 + 2];

    const int p0 = parents[n * 3 + 0];
    const int p1 = parents[n * 3 + 1];
    const int p2 = parents[n * 3 + 2];

    const float* vb = verts + (size_t)b * NVq * 2;
    const float cx = w0 * vb[p0 * 2 + 0] + w1 * vb[p1 * 2 + 0] + w2 * vb[p2 * 2 + 0];
    const float cy = w0 * vb[p0 * 2 + 1] + w1 * vb[p1 * 2 + 1] + w2 * vb[p2 * 2 + 1];

    // replicate reference's normalize -> denormalize round-trip exactly
    const float gx = cx / (float)(Wq - 1) * 2.0f - 1.0f;
    const float gy = cy / (float)(Hq - 1) * 2.0f - 1.0f;

    SampleParams sp;
    sp.px = (gx + 1.0f) * 0.5f * (float)(Wq - 1);
    sp.py = (gy + 1.0f) * 0.5f * (float)(Hq - 1);
    sp.b  = b;
    return sp;
}

// ---------------------------------------------------------------------------
// K1: transpose + quantize (B,C,H,W) fp32 -> (B,H,W,C) bf16.
// fm is read-once -> NT loads; fmtb we WANT resident in L2/L3 -> normal stores.
// ---------------------------------------------------------------------------
__global__ __launch_bounds__(256) void transpose_kernel(
    const float* __restrict__ fm, unsigned short* __restrict__ fmtb)
{
    __shared__ float tile[64][65];
    const int blk = blockIdx.x;                 // 0 .. B*(HW/64)-1
    const int b   = blk / (Hq * Wq / 64);
    const int hw0 = (blk % (Hq * Wq / 64)) * 64;
    const int t   = threadIdx.x;
    const int tx  = t & 63;
    const int ty  = t >> 6;

    const float* src = fm + (size_t)b * Cq * (Hq * Wq);
    #pragma unroll
    for (int c = ty; c < 64; c += 4) {
        tile[c][tx] = __builtin_nontemporal_load(
            src + (size_t)c * (Hq * Wq) + hw0 + tx);           // coalesced
    }
    __syncthreads();

    // store: 8 pixels per iter; 32 lanes/pixel, each lane packs 2 bf16 ch.
    unsigned int* dstu = (unsigned int*)(fmtb + ((size_t)b * (Hq * Wq) + hw0) * Cq);
    const int c2 = (t & 31) * 2;
    #pragma unroll
    for (int r0 = 0; r0 < 64; r0 += 8) {
        const int p = r0 + (t >> 5);
        const unsigned int lo = f2bf(tile[c2][p]);
        const unsigned int hi = f2bf(tile[c2 + 1][p]);
        dstu[p * 32 + (c2 >> 1)] = lo | (hi << 16);            // 256B/wave
    }
}

// ---------------------------------------------------------------------------
// K2 (fused two-phase): Phase A per-thread params -> LDS;
// Phase B: 8 lanes/n x 8 bf16 channels. NT output stores (R3/R5 A/B: NT wins,
// keeps the map L2/L3-resident). unroll-4 batches: params to regs, 16 corner
// loads hoisted in flight before the fma/store cluster (latency hiding).
// ---------------------------------------------------------------------------
__global__ __launch_bounds__(256) void sample_kernel(
    const unsigned short* __restrict__ fmtb,  // (B,H,W,C) bf16
    const float* __restrict__ verts,
    const float* __restrict__ bary,
    const int*   __restrict__ parents,
    float* __restrict__ out)                  // (B,N,C) fp32
{
    __shared__ int   s_ofs[256][4];
    __shared__ float s_wts[256][4];

    const int t     = threadIdx.x;
    const int gbase = blockIdx.x * 256;
    const int g     = gbase + t;

    // ---------------- Phase A ----------------
    if (g < TOTAL) {
        SampleParams sp = compute_center(g, verts, bary, parents);
        const float x0f = floorf(sp.px);
        const float y0f = floorf(sp.py);
        const float fx = sp.px - x0f;
        const float fy = sp.py - y0f;

        const int ix0 = (int)x0f, iy0 = (int)y0f;
        const int ix1 = ix0 + 1,  iy1 = iy0 + 1;

        const float vx0 = (x0f >= 0.0f        && x0f <= (float)(Wq - 1)) ? 1.0f : 0.0f;
        const float vx1 = (x0f + 1.0f >= 0.0f && x0f + 1.0f <= (float)(Wq - 1)) ? 1.0f : 0.0f;
        const float vy0 = (y0f >= 0.0f        && y0f <= (float)(Hq - 1)) ? 1.0f : 0.0f;
        const float vy1 = (y0f + 1.0f >= 0.0f && y0f + 1.0f <= (float)(Hq - 1)) ? 1.0f : 0.0f;

        const int cx0 = min(max(ix0, 0), Wq - 1);
        const int cx1 = min(max(ix1, 0), Wq - 1);
        const int cy0 = min(max(iy0, 0), Hq - 1);
        const int cy1 = min(max(iy1, 0), Hq - 1);

        const int bb = sp.b * (Hq * Wq * Cq);
        s_ofs[t][0] = bb + (cy0 * Wq + cx0) * Cq;
        s_ofs[t][1] = bb + (cy0 * Wq + cx1) * Cq;
        s_ofs[t][2] = bb + (cy1 * Wq + cx0) * Cq;
        s_ofs[t][3] = bb + (cy1 * Wq + cx1) * Cq;

        s_wts[t][0] = (1.0f - fx) * (1.0f - fy) * vx0 * vy0;
        s_wts[t][1] = fx          * (1.0f - fy) * vx1 * vy0;
        s_wts[t][2] = (1.0f - fx) * fy          * vx0 * vy1;
        s_wts[t][3] = fx          * fy          * vx1 * vy1;
    } else {
        s_ofs[t][0] = s_ofs[t][1] = s_ofs[t][2] = s_ofs[t][3] = 0;
        s_wts[t][0] = s_wts[t][1] = s_wts[t][2] = s_wts[t][3] = 0.0f;
    }
    __syncthreads();

    // ---------------- Phase B ----------------
    const int wv   = t >> 6;
    const int lane = t & 63;
    const int q    = lane >> 3;          // 0..7 -> which n in group of 8
    const int c8   = (lane & 7) * 8;     // 8 channels per lane

    const bool full = (gbase + 256 <= TOTAL);

    if (full) {
        // two batches of 4 iterations; within a batch: params -> 16 loads
        // in flight -> fma+store. __restrict__ lets loads hoist over stores.
        #pragma unroll
        for (int half = 0; half < 2; ++half) {
            int4   o[4];
            float4 w[4];
            u16x8  a[4][4];
            #pragma unroll
            for (int i = 0; i < 4; ++i) {
                const int li = wv * 64 + (half * 4 + i) * 8 + q;
                o[i] = *(const int4*)  s_ofs[li];
                w[i] = *(const float4*)s_wts[li];
            }
            #pragma unroll
            for (int i = 0; i < 4; ++i) {
                a[i][0] = *(const u16x8*)(fmtb + o[i].x + c8);
                a[i][1] = *(const u16x8*)(fmtb + o[i].y + c8);
                a[i][2] = *(const u16x8*)(fmtb + o[i].z + c8);
                a[i][3] = *(const u16x8*)(fmtb + o[i].w + c8);
            }
            #pragma unroll
            for (int i = 0; i < 4; ++i) {
                const int li = wv * 64 + (half * 4 + i) * 8 + q;
                f32x4 lo, hi;
                #pragma unroll
                for (int j = 0; j < 4; ++j) {
                    lo[j] = bf2f(a[i][0][j]) * w[i].x + bf2f(a[i][1][j]) * w[i].y
                          + bf2f(a[i][2][j]) * w[i].z + bf2f(a[i][3][j]) * w[i].w;
                }
                #pragma unroll
                for (int j = 0; j < 4; ++j) {
                    hi[j] = bf2f(a[i][0][4+j]) * w[i].x + bf2f(a[i][1][4+j]) * w[i].y
                          + bf2f(a[i][2][4+j]) * w[i].z + bf2f(a[i][3][4+j]) * w[i].w;
                }
                float* op = out + (size_t)(gbase + li) * Cq + c8;
                __builtin_nontemporal_store(lo, (f32x4*)op);
                __builtin_nontemporal_store(hi, (f32x4*)(op + 4));
            }
        }
    } else {
        #pragma unroll 2
        for (int i = 0; i < 8; ++i) {
            const int li = wv * 64 + i * 8 + q;
            if (gbase + li >= TOTAL) continue;

            const int4   o = *(const int4*)  s_ofs[li];
            const float4 w = *(const float4*)s_wts[li];

            const u16x8 a0 = *(const u16x8*)(fmtb + o.x + c8);
            const u16x8 a1 = *(const u16x8*)(fmtb + o.y + c8);
            const u16x8 a2 = *(const u16x8*)(fmtb + o.z + c8);
            const u16x8 a3 = *(const u16x8*)(fmtb + o.w + c8);

            f32x4 lo, hi;
            #pragma unroll
            for (int j = 0; j < 4; ++j) {
                lo[j] = bf2f(a0[j]) * w.x + bf2f(a1[j]) * w.y
                      + bf2f(a2[j]) * w.z + bf2f(a3[j]) * w.w;
            }
            #pragma unroll
            for (int j = 0; j < 4; ++j) {
                hi[j] = bf2f(a0[4+j]) * w.x + bf2f(a1[4+j]) * w.y
                      + bf2f(a2[4+j]) * w.z + bf2f(a3[4+j]) * w.w;
            }
            float* op = out + (size_t)(gbase + li) * Cq + c8;
            __builtin_nontemporal_store(lo, (f32x4*)op);
            __builtin_nontemporal_store(hi, (f32x4*)(op + 4));
        }
    }
}

// ---------------------------------------------------------------------------
// Fallback (workspace too small): sample directly from (B,C,H,W), fp32 exact.
// ---------------------------------------------------------------------------
__global__ __launch_bounds__(256) void sample_direct_kernel(
    const float* __restrict__ fm,
    const float* __restrict__ verts,
    const float* __restrict__ bary,
    const int*   __restrict__ parents,
    float* __restrict__ out)
{
    const int g = blockIdx.x * 4 + (threadIdx.x >> 6);
    if (g >= TOTAL) return;
    const int lane = threadIdx.x & 63;

    SampleParams sp = compute_center(g, verts, bary, parents);
    const float x0f = floorf(sp.px);
    const float y0f = floorf(sp.py);
    const float fx = sp.px - x0f;
    const float fy = sp.py - y0f;

    const int ix0 = (int)x0f, iy0 = (int)y0f;
    const int ix1 = ix0 + 1,  iy1 = iy0 + 1;

    const float vx0 = (x0f >= 0.0f        && x0f <= (float)(Wq - 1)) ? 1.0f : 0.0f;
    const float vx1 = (x0f + 1.0f >= 0.0f && x0f + 1.0f <= (float)(Wq - 1)) ? 1.0f : 0.0f;
    const float vy0 = (y0f >= 0.0f        && y0f <= (float)(Hq - 1)) ? 1.0f : 0.0f;
    const float vy1 = (y0f + 1.0f >= 0.0f && y0f + 1.0f <= (float)(Hq - 1)) ? 1.0f : 0.0f;

    const int cx0 = min(max(ix0, 0), Wq - 1);
    const int cx1 = min(max(ix1, 0), Wq - 1);
    const int cy0 = min(max(iy0, 0), Hq - 1);
    const int cy1 = min(max(iy1, 0), Hq - 1);

    const float* base = fm + ((size_t)sp.b * Cq + lane) * (Hq * Wq);
    const float v00 = base[cy0 * Wq + cx0] * (vx0 * vy0);
    const float v01 = base[cy0 * Wq + cx1] * (vx1 * vy0);
    const float v10 = base[cy1 * Wq + cx0] * (vx0 * vy1);
    const float v11 = base[cy1 * Wq + cx1] * (vx1 * vy1);

    const float res = (v00 * (1.0f - fx) + v01 * fx) * (1.0f - fy)
                    + (v10 * (1.0f - fx) + v11 * fx) * fy;

    out[(size_t)g * Cq + lane] = res;
}

extern "C" void kernel_launch(void* const* d_in, const int* in_sizes, int n_in,
                              void* d_out, int out_size, void* d_ws, size_t ws_size,
                              hipStream_t stream)
{
    const float* fm      = (const float*)d_in[0];   // (B,C,H,W) fp32
    const float* verts   = (const float*)d_in[1];   // (B,NV,2) fp32
    const float* bary    = (const float*)d_in[2];   // (K,3) fp32
    const int*   parents = (const int*)  d_in[3];   // (N,3) int32
    float* out = (float*)d_out;                     // (B,N,C) fp32

    const int nblk_s = (TOTAL + 255) / 256;     // 4688
    const int nblk_t = Bq * (Hq * Wq / 64);     // 4096

    if (ws_size >= SZ_FMTB) {
        unsigned short* fmtb = (unsigned short*)d_ws;
        transpose_kernel<<<nblk_t, 256, 0, stream>>>(fm, fmtb);
        sample_kernel<<<nblk_s, 256, 0, stream>>>(fmtb, verts, bary, parents, out);
    } else {
        sample_direct_kernel<<<(TOTAL + 3) / 4, 256, 0, stream>>>(fm, verts, bary, parents, out);
    }
}

// Round 8
// 117.595 us; speedup vs baseline: 1.4647x; 1.0802x over previous
//
#include <hip/hip_runtime.h>
#include <hip/hip_bf16.h>

// Problem constants (fixed by the reference file).
#define Bq  4
#define Cq  64
#define Hq  256
#define Wq  256
#define Nq  300000
#define Kq  16
#define NVq 6890
#define TOTAL (Bq * Nq)

#define SZ_FMTB ((size_t)Bq * Hq * Wq * Cq * 2)   // 32 MiB bf16 map

typedef float          f32x4 __attribute__((ext_vector_type(4)));
typedef unsigned short u16x4 __attribute__((ext_vector_type(4)));

__device__ __forceinline__ float bf2f(unsigned short u) {
    return __uint_as_float(((unsigned)u) << 16);
}
__device__ __forceinline__ unsigned short f2bf(float x) {
    __hip_bfloat16 v = __float2bfloat16(x);   // RNE
    return *reinterpret_cast<unsigned short*>(&v);
}

// Shared per-n scalar pipeline: flat g -> pixel-space sample point.
struct SampleParams { float px, py; int b; };
__device__ __forceinline__ SampleParams compute_center(
    int g, const float* __restrict__ verts, const float* __restrict__ bary,
    const int* __restrict__ parents)
{
    const int b = g / Nq;
    const int n = g - b * Nq;

    const int k = n & (Kq - 1);
    const float w0 = bary[k * 3 + 0];
    const float w1 = bary[k * 3 + 1];
    const float w2 = bary[k * 3 + 2];

    const int p0 = parents[n * 3 + 0];
    const int p1 = parents[n * 3 + 1];
    const int p2 = parents[n * 3 + 2];

    const float* vb = verts + (size_t)b * NVq * 2;
    const float cx = w0 * vb[p0 * 2 + 0] + w1 * vb[p1 * 2 + 0] + w2 * vb[p2 * 2 + 0];
    const float cy = w0 * vb[p0 * 2 + 1] + w1 * vb[p1 * 2 + 1] + w2 * vb[p2 * 2 + 1];

    // replicate reference's normalize -> denormalize round-trip exactly
    const float gx = cx / (float)(Wq - 1) * 2.0f - 1.0f;
    const float gy = cy / (float)(Hq - 1) * 2.0f - 1.0f;

    SampleParams sp;
    sp.px = (gx + 1.0f) * 0.5f * (float)(Wq - 1);
    sp.py = (gy + 1.0f) * 0.5f * (float)(Hq - 1);
    sp.b  = b;
    return sp;
}

// ---------------------------------------------------------------------------
// K1: transpose + quantize (B,C,H,W) fp32 -> (B,H,W,C) bf16.
// fm is read-once -> NT loads; fmtb we WANT resident in L2/L3 -> normal stores.
// ---------------------------------------------------------------------------
__global__ __launch_bounds__(256) void transpose_kernel(
    const float* __restrict__ fm, unsigned short* __restrict__ fmtb)
{
    __shared__ float tile[64][65];
    const int blk = blockIdx.x;                 // 0 .. B*(HW/64)-1
    const int b   = blk / (Hq * Wq / 64);
    const int hw0 = (blk % (Hq * Wq / 64)) * 64;
    const int t   = threadIdx.x;
    const int tx  = t & 63;
    const int ty  = t >> 6;

    const float* src = fm + (size_t)b * Cq * (Hq * Wq);
    #pragma unroll
    for (int c = ty; c < 64; c += 4) {
        tile[c][tx] = __builtin_nontemporal_load(
            src + (size_t)c * (Hq * Wq) + hw0 + tx);           // coalesced
    }
    __syncthreads();

    // store: 8 pixels per iter; 32 lanes/pixel, each lane packs 2 bf16 ch.
    unsigned int* dstu = (unsigned int*)(fmtb + ((size_t)b * (Hq * Wq) + hw0) * Cq);
    const int c2 = (t & 31) * 2;
    #pragma unroll
    for (int r0 = 0; r0 < 64; r0 += 8) {
        const int p = r0 + (t >> 5);
        const unsigned int lo = f2bf(tile[c2][p]);
        const unsigned int hi = f2bf(tile[c2 + 1][p]);
        dstu[p * 32 + (c2 >> 1)] = lo | (hi << 16);            // 256B/wave
    }
}

// ---------------------------------------------------------------------------
// K2 (fused two-phase): Phase A per-thread params -> LDS;
// Phase B: 8 lanes/n. Channel split per lane = {cA..cA+3, cA+32..cA+35} so
// each NT store instruction writes 8x 128-B LINE-COMPLETE contiguous chunks
// (lanes 0-7 cover one n's bytes 0..127) -- no sector-fragmented NT
// writebacks. Loads are 2x 8B per corner (same cache-line traffic).
// ---------------------------------------------------------------------------
__global__ __launch_bounds__(256) void sample_kernel(
    const unsigned short* __restrict__ fmtb,  // (B,H,W,C) bf16
    const float* __restrict__ verts,
    const float* __restrict__ bary,
    const int*   __restrict__ parents,
    float* __restrict__ out)                  // (B,N,C) fp32
{
    __shared__ int   s_ofs[256][4];
    __shared__ float s_wts[256][4];

    const int t     = threadIdx.x;
    const int gbase = blockIdx.x * 256;
    const int g     = gbase + t;

    // ---------------- Phase A ----------------
    if (g < TOTAL) {
        SampleParams sp = compute_center(g, verts, bary, parents);
        const float x0f = floorf(sp.px);
        const float y0f = floorf(sp.py);
        const float fx = sp.px - x0f;
        const float fy = sp.py - y0f;

        const int ix0 = (int)x0f, iy0 = (int)y0f;
        const int ix1 = ix0 + 1,  iy1 = iy0 + 1;

        const float vx0 = (x0f >= 0.0f        && x0f <= (float)(Wq - 1)) ? 1.0f : 0.0f;
        const float vx1 = (x0f + 1.0f >= 0.0f && x0f + 1.0f <= (float)(Wq - 1)) ? 1.0f : 0.0f;
        const float vy0 = (y0f >= 0.0f        && y0f <= (float)(Hq - 1)) ? 1.0f : 0.0f;
        const float vy1 = (y0f + 1.0f >= 0.0f && y0f + 1.0f <= (float)(Hq - 1)) ? 1.0f : 0.0f;

        const int cx0 = min(max(ix0, 0), Wq - 1);
        const int cx1 = min(max(ix1, 0), Wq - 1);
        const int cy0 = min(max(iy0, 0), Hq - 1);
        const int cy1 = min(max(iy1, 0), Hq - 1);

        const int bb = sp.b * (Hq * Wq * Cq);
        s_ofs[t][0] = bb + (cy0 * Wq + cx0) * Cq;
        s_ofs[t][1] = bb + (cy0 * Wq + cx1) * Cq;
        s_ofs[t][2] = bb + (cy1 * Wq + cx0) * Cq;
        s_ofs[t][3] = bb + (cy1 * Wq + cx1) * Cq;

        s_wts[t][0] = (1.0f - fx) * (1.0f - fy) * vx0 * vy0;
        s_wts[t][1] = fx          * (1.0f - fy) * vx1 * vy0;
        s_wts[t][2] = (1.0f - fx) * fy          * vx0 * vy1;
        s_wts[t][3] = fx          * fy          * vx1 * vy1;
    } else {
        s_ofs[t][0] = s_ofs[t][1] = s_ofs[t][2] = s_ofs[t][3] = 0;
        s_wts[t][0] = s_wts[t][1] = s_wts[t][2] = s_wts[t][3] = 0.0f;
    }
    __syncthreads();

    // ---------------- Phase B ----------------
    const int wv   = t >> 6;
    const int lane = t & 63;
    const int q    = lane >> 3;          // 0..7 -> which n in group of 8
    const int cA   = (lane & 7) * 4;     // channels cA..cA+3 and cA+32..cA+35

    const bool full = (gbase + 256 <= TOTAL);

    #pragma unroll 2
    for (int i = 0; i < 8; ++i) {
        const int li = wv * 64 + i * 8 + q;
        if (!full && gbase + li >= TOTAL) continue;

        const int4   o = *(const int4*)  s_ofs[li];
        const float4 w = *(const float4*)s_wts[li];

        const u16x4 a0A = *(const u16x4*)(fmtb + o.x + cA);
        const u16x4 a1A = *(const u16x4*)(fmtb + o.y + cA);
        const u16x4 a2A = *(const u16x4*)(fmtb + o.z + cA);
        const u16x4 a3A = *(const u16x4*)(fmtb + o.w + cA);
        const u16x4 a0B = *(const u16x4*)(fmtb + o.x + cA + 32);
        const u16x4 a1B = *(const u16x4*)(fmtb + o.y + cA + 32);
        const u16x4 a2B = *(const u16x4*)(fmtb + o.z + cA + 32);
        const u16x4 a3B = *(const u16x4*)(fmtb + o.w + cA + 32);

        f32x4 rA, rB;
        #pragma unroll
        for (int j = 0; j < 4; ++j) {
            rA[j] = bf2f(a0A[j]) * w.x + bf2f(a1A[j]) * w.y
                  + bf2f(a2A[j]) * w.z + bf2f(a3A[j]) * w.w;
        }
        #pragma unroll
        for (int j = 0; j < 4; ++j) {
            rB[j] = bf2f(a0B[j]) * w.x + bf2f(a1B[j]) * w.y
                  + bf2f(a2B[j]) * w.z + bf2f(a3B[j]) * w.w;
        }

        float* op = out + (size_t)(gbase + li) * Cq;
        __builtin_nontemporal_store(rA, (f32x4*)(op + cA));        // line-complete
        __builtin_nontemporal_store(rB, (f32x4*)(op + cA + 32));   // line-complete
    }
}

// ---------------------------------------------------------------------------
// Fallback (workspace too small): sample directly from (B,C,H,W), fp32 exact.
// ---------------------------------------------------------------------------
__global__ __launch_bounds__(256) void sample_direct_kernel(
    const float* __restrict__ fm,
    const float* __restrict__ verts,
    const float* __restrict__ bary,
    const int*   __restrict__ parents,
    float* __restrict__ out)
{
    const int g = blockIdx.x * 4 + (threadIdx.x >> 6);
    if (g >= TOTAL) return;
    const int lane = threadIdx.x & 63;

    SampleParams sp = compute_center(g, verts, bary, parents);
    const float x0f = floorf(sp.px);
    const float y0f = floorf(sp.py);
    const float fx = sp.px - x0f;
    const float fy = sp.py - y0f;

    const int ix0 = (int)x0f, iy0 = (int)y0f;
    const int ix1 = ix0 + 1,  iy1 = iy0 + 1;

    const float vx0 = (x0f >= 0.0f        && x0f <= (float)(Wq - 1)) ? 1.0f : 0.0f;
    const float vx1 = (x0f + 1.0f >= 0.0f && x0f + 1.0f <= (float)(Wq - 1)) ? 1.0f : 0.0f;
    const float vy0 = (y0f >= 0.0f        && y0f <= (float)(Hq - 1)) ? 1.0f : 0.0f;
    const float vy1 = (y0f + 1.0f >= 0.0f && y0f + 1.0f <= (float)(Hq - 1)) ? 1.0f : 0.0f;

    const int cx0 = min(max(ix0, 0), Wq - 1);
    const int cx1 = min(max(ix1, 0), Wq - 1);
    const int cy0 = min(max(iy0, 0), Hq - 1);
    const int cy1 = min(max(iy1, 0), Hq - 1);

    const float* base = fm + ((size_t)sp.b * Cq + lane) * (Hq * Wq);
    const float v00 = base[cy0 * Wq + cx0] * (vx0 * vy0);
    const float v01 = base[cy0 * Wq + cx1] * (vx1 * vy0);
    const float v10 = base[cy1 * Wq + cx0] * (vx0 * vy1);
    const float v11 = base[cy1 * Wq + cx1] * (vx1 * vy1);

    const float res = (v00 * (1.0f - fx) + v01 * fx) * (1.0f - fy)
                    + (v10 * (1.0f - fx) + v11 * fx) * fy;

    out[(size_t)g * Cq + lane] = res;
}

extern "C" void kernel_launch(void* const* d_in, const int* in_sizes, int n_in,
                              void* d_out, int out_size, void* d_ws, size_t ws_size,
                              hipStream_t stream)
{
    const float* fm      = (const float*)d_in[0];   // (B,C,H,W) fp32
    const float* verts   = (const float*)d_in[1];   // (B,NV,2) fp32
    const float* bary    = (const float*)d_in[2];   // (K,3) fp32
    const int*   parents = (const int*)  d_in[3];   // (N,3) int32
    float* out = (float*)d_out;                     // (B,N,C) fp32

    const int nblk_s = (TOTAL + 255) / 256;     // 4688
    const int nblk_t = Bq * (Hq * Wq / 64);     // 4096

    if (ws_size >= SZ_FMTB) {
        unsigned short* fmtb = (unsigned short*)d_ws;
        transpose_kernel<<<nblk_t, 256, 0, stream>>>(fm, fmtb);
        sample_kernel<<<nblk_s, 256, 0, stream>>>(fmtb, verts, bary, parents, out);
    } else {
        sample_direct_kernel<<<(TOTAL + 3) / 4, 256, 0, stream>>>(fm, verts, bary, parents, out);
    }
}

// Round 9
// 109.028 us; speedup vs baseline: 1.5798x; 1.0786x over previous
//
#include <hip/hip_runtime.h>
#include <hip/hip_bf16.h>

// Problem constants (fixed by the reference file).
#define Bq  4
#define Cq  64
#define Hq  256
#define Wq  256
#define Nq  300000
#define Kq  16
#define NVq 6890
#define TOTAL (Bq * Nq)

#define SZ_FMTB ((size_t)Bq * Hq * Wq * Cq * 2)   // 32 MiB bf16 map

#define NXCD 8
#define NBLK_S ((TOTAL + 255) / 256)              // 4688 = 8 * 586, clean

typedef float          f32x4 __attribute__((ext_vector_type(4)));
typedef unsigned short u16x4 __attribute__((ext_vector_type(4)));

__device__ __forceinline__ float bf2f(unsigned short u) {
    return __uint_as_float(((unsigned)u) << 16);
}
__device__ __forceinline__ unsigned short f2bf(float x) {
    __hip_bfloat16 v = __float2bfloat16(x);   // RNE
    return *reinterpret_cast<unsigned short*>(&v);
}

// Shared per-n scalar pipeline: flat g -> pixel-space sample point.
struct SampleParams { float px, py; int b; };
__device__ __forceinline__ SampleParams compute_center(
    int g, const float* __restrict__ verts, const float* __restrict__ bary,
    const int* __restrict__ parents)
{
    const int b = g / Nq;
    const int n = g - b * Nq;

    const int k = n & (Kq - 1);
    const float w0 = bary[k * 3 + 0];
    const float w1 = bary[k * 3 + 1];
    const float w2 = bary[k * 3 + 2];

    const int p0 = parents[n * 3 + 0];
    const int p1 = parents[n * 3 + 1];
    const int p2 = parents[n * 3 + 2];

    const float* vb = verts + (size_t)b * NVq * 2;
    const float cx = w0 * vb[p0 * 2 + 0] + w1 * vb[p1 * 2 + 0] + w2 * vb[p2 * 2 + 0];
    const float cy = w0 * vb[p0 * 2 + 1] + w1 * vb[p1 * 2 + 1] + w2 * vb[p2 * 2 + 1];

    // replicate reference's normalize -> denormalize round-trip exactly
    const float gx = cx / (float)(Wq - 1) * 2.0f - 1.0f;
    const float gy = cy / (float)(Hq - 1) * 2.0f - 1.0f;

    SampleParams sp;
    sp.px = (gx + 1.0f) * 0.5f * (float)(Wq - 1);
    sp.py = (gy + 1.0f) * 0.5f * (float)(Hq - 1);
    sp.b  = b;
    return sp;
}

// ---------------------------------------------------------------------------
// K1: transpose + quantize (B,C,H,W) fp32 -> (B,H,W,C) bf16.
// fm is read-once -> NT loads; fmtb we WANT resident in L2/L3 -> normal stores.
// ---------------------------------------------------------------------------
__global__ __launch_bounds__(256) void transpose_kernel(
    const float* __restrict__ fm, unsigned short* __restrict__ fmtb)
{
    __shared__ float tile[64][65];
    const int blk = blockIdx.x;                 // 0 .. B*(HW/64)-1
    const int b   = blk / (Hq * Wq / 64);
    const int hw0 = (blk % (Hq * Wq / 64)) * 64;
    const int t   = threadIdx.x;
    const int tx  = t & 63;
    const int ty  = t >> 6;

    const float* src = fm + (size_t)b * Cq * (Hq * Wq);
    #pragma unroll
    for (int c = ty; c < 64; c += 4) {
        tile[c][tx] = __builtin_nontemporal_load(
            src + (size_t)c * (Hq * Wq) + hw0 + tx);           // coalesced
    }
    __syncthreads();

    // store: 8 pixels per iter; 32 lanes/pixel, each lane packs 2 bf16 ch.
    unsigned int* dstu = (unsigned int*)(fmtb + ((size_t)b * (Hq * Wq) + hw0) * Cq);
    const int c2 = (t & 31) * 2;
    #pragma unroll
    for (int r0 = 0; r0 < 64; r0 += 8) {
        const int p = r0 + (t >> 5);
        const unsigned int lo = f2bf(tile[c2][p]);
        const unsigned int hi = f2bf(tile[c2 + 1][p]);
        dstu[p * 32 + (c2 >> 1)] = lo | (hi << 16);            // 256B/wave
    }
}

// ---------------------------------------------------------------------------
// K2 (fused two-phase): Phase A per-thread params -> LDS;
// Phase B: 8 lanes/n, channel split {cA..cA+3, cA+32..cA+35}: each NT store
// instruction writes 8x 128-B line-complete chunks.
// NEW: chunked XCD swizzle of blockIdx (bijective; 4688 = 8*586): each XCD
// processes one contiguous g-chunk => its random gathers stay inside ONE
// batch's 8 MB map slice for the XCD's whole lifetime => ~2x better per-XCD
// L2 hit rate on gathers. Writes remain linear within each chunk.
// ---------------------------------------------------------------------------
__global__ __launch_bounds__(256) void sample_kernel(
    const unsigned short* __restrict__ fmtb,  // (B,H,W,C) bf16
    const float* __restrict__ verts,
    const float* __restrict__ bary,
    const int*   __restrict__ parents,
    float* __restrict__ out)                  // (B,N,C) fp32
{
    __shared__ int   s_ofs[256][4];
    __shared__ float s_wts[256][4];

    const int t = threadIdx.x;

    // chunked bijective XCD swizzle: dispatch round-robins XCDs, so block
    // bid lands on XCD bid%8; give that XCD the bid/8-th block of its own
    // contiguous chunk of the grid.
    const int bid   = (int)blockIdx.x;
    const int blk   = (bid % NXCD) * (NBLK_S / NXCD) + bid / NXCD;
    const int gbase = blk * 256;
    const int g     = gbase + t;

    // ---------------- Phase A ----------------
    if (g < TOTAL) {
        SampleParams sp = compute_center(g, verts, bary, parents);
        const float x0f = floorf(sp.px);
        const float y0f = floorf(sp.py);
        const float fx = sp.px - x0f;
        const float fy = sp.py - y0f;

        const int ix0 = (int)x0f, iy0 = (int)y0f;
        const int ix1 = ix0 + 1,  iy1 = iy0 + 1;

        const float vx0 = (x0f >= 0.0f        && x0f <= (float)(Wq - 1)) ? 1.0f : 0.0f;
        const float vx1 = (x0f + 1.0f >= 0.0f && x0f + 1.0f <= (float)(Wq - 1)) ? 1.0f : 0.0f;
        const float vy0 = (y0f >= 0.0f        && y0f <= (float)(Hq - 1)) ? 1.0f : 0.0f;
        const float vy1 = (y0f + 1.0f >= 0.0f && y0f + 1.0f <= (float)(Hq - 1)) ? 1.0f : 0.0f;

        const int cx0 = min(max(ix0, 0), Wq - 1);
        const int cx1 = min(max(ix1, 0), Wq - 1);
        const int cy0 = min(max(iy0, 0), Hq - 1);
        const int cy1 = min(max(iy1, 0), Hq - 1);

        const int bb = sp.b * (Hq * Wq * Cq);
        s_ofs[t][0] = bb + (cy0 * Wq + cx0) * Cq;
        s_ofs[t][1] = bb + (cy0 * Wq + cx1) * Cq;
        s_ofs[t][2] = bb + (cy1 * Wq + cx0) * Cq;
        s_ofs[t][3] = bb + (cy1 * Wq + cx1) * Cq;

        s_wts[t][0] = (1.0f - fx) * (1.0f - fy) * vx0 * vy0;
        s_wts[t][1] = fx          * (1.0f - fy) * vx1 * vy0;
        s_wts[t][2] = (1.0f - fx) * fy          * vx0 * vy1;
        s_wts[t][3] = fx          * fy          * vx1 * vy1;
    } else {
        s_ofs[t][0] = s_ofs[t][1] = s_ofs[t][2] = s_ofs[t][3] = 0;
        s_wts[t][0] = s_wts[t][1] = s_wts[t][2] = s_wts[t][3] = 0.0f;
    }
    __syncthreads();

    // ---------------- Phase B ----------------
    const int wv   = t >> 6;
    const int lane = t & 63;
    const int q    = lane >> 3;          // 0..7 -> which n in group of 8
    const int cA   = (lane & 7) * 4;     // channels cA..cA+3 and cA+32..cA+35

    const bool full = (gbase + 256 <= TOTAL);

    #pragma unroll 2
    for (int i = 0; i < 8; ++i) {
        const int li = wv * 64 + i * 8 + q;
        if (!full && gbase + li >= TOTAL) continue;

        const int4   o = *(const int4*)  s_ofs[li];
        const float4 w = *(const float4*)s_wts[li];

        const u16x4 a0A = *(const u16x4*)(fmtb + o.x + cA);
        const u16x4 a1A = *(const u16x4*)(fmtb + o.y + cA);
        const u16x4 a2A = *(const u16x4*)(fmtb + o.z + cA);
        const u16x4 a3A = *(const u16x4*)(fmtb + o.w + cA);
        const u16x4 a0B = *(const u16x4*)(fmtb + o.x + cA + 32);
        const u16x4 a1B = *(const u16x4*)(fmtb + o.y + cA + 32);
        const u16x4 a2B = *(const u16x4*)(fmtb + o.z + cA + 32);
        const u16x4 a3B = *(const u16x4*)(fmtb + o.w + cA + 32);

        f32x4 rA, rB;
        #pragma unroll
        for (int j = 0; j < 4; ++j) {
            rA[j] = bf2f(a0A[j]) * w.x + bf2f(a1A[j]) * w.y
                  + bf2f(a2A[j]) * w.z + bf2f(a3A[j]) * w.w;
        }
        #pragma unroll
        for (int j = 0; j < 4; ++j) {
            rB[j] = bf2f(a0B[j]) * w.x + bf2f(a1B[j]) * w.y
                  + bf2f(a2B[j]) * w.z + bf2f(a3B[j]) * w.w;
        }

        float* op = out + (size_t)(gbase + li) * Cq;
        __builtin_nontemporal_store(rA, (f32x4*)(op + cA));        // line-complete
        __builtin_nontemporal_store(rB, (f32x4*)(op + cA + 32));   // line-complete
    }
}

// ---------------------------------------------------------------------------
// Fallback (workspace too small): sample directly from (B,C,H,W), fp32 exact.
// ---------------------------------------------------------------------------
__global__ __launch_bounds__(256) void sample_direct_kernel(
    const float* __restrict__ fm,
    const float* __restrict__ verts,
    const float* __restrict__ bary,
    const int*   __restrict__ parents,
    float* __restrict__ out)
{
    const int g = blockIdx.x * 4 + (threadIdx.x >> 6);
    if (g >= TOTAL) return;
    const int lane = threadIdx.x & 63;

    SampleParams sp = compute_center(g, verts, bary, parents);
    const float x0f = floorf(sp.px);
    const float y0f = floorf(sp.py);
    const float fx = sp.px - x0f;
    const float fy = sp.py - y0f;

    const int ix0 = (int)x0f, iy0 = (int)y0f;
    const int ix1 = ix0 + 1,  iy1 = iy0 + 1;

    const float vx0 = (x0f >= 0.0f        && x0f <= (float)(Wq - 1)) ? 1.0f : 0.0f;
    const float vx1 = (x0f + 1.0f >= 0.0f && x0f + 1.0f <= (float)(Wq - 1)) ? 1.0f : 0.0f;
    const float vy0 = (y0f >= 0.0f        && y0f <= (float)(Hq - 1)) ? 1.0f : 0.0f;
    const float vy1 = (y0f + 1.0f >= 0.0f && y0f + 1.0f <= (float)(Hq - 1)) ? 1.0f : 0.0f;

    const int cx0 = min(max(ix0, 0), Wq - 1);
    const int cx1 = min(max(ix1, 0), Wq - 1);
    const int cy0 = min(max(iy0, 0), Hq - 1);
    const int cy1 = min(max(iy1, 0), Hq - 1);

    const float* base = fm + ((size_t)sp.b * Cq + lane) * (Hq * Wq);
    const float v00 = base[cy0 * Wq + cx0] * (vx0 * vy0);
    const float v01 = base[cy0 * Wq + cx1] * (vx1 * vy0);
    const float v10 = base[cy1 * Wq + cx0] * (vx0 * vy1);
    const float v11 = base[cy1 * Wq + cx1] * (vx1 * vy1);

    const float res = (v00 * (1.0f - fx) + v01 * fx) * (1.0f - fy)
                    + (v10 * (1.0f - fx) + v11 * fx) * fy;

    out[(size_t)g * Cq + lane] = res;
}

extern "C" void kernel_launch(void* const* d_in, const int* in_sizes, int n_in,
                              void* d_out, int out_size, void* d_ws, size_t ws_size,
                              hipStream_t stream)
{
    const float* fm      = (const float*)d_in[0];   // (B,C,H,W) fp32
    const float* verts   = (const float*)d_in[1];   // (B,NV,2) fp32
    const float* bary    = (const float*)d_in[2];   // (K,3) fp32
    const int*   parents = (const int*)  d_in[3];   // (N,3) int32
    float* out = (float*)d_out;                     // (B,N,C) fp32

    const int nblk_t = Bq * (Hq * Wq / 64);     // 4096

    if (ws_size >= SZ_FMTB) {
        unsigned short* fmtb = (unsigned short*)d_ws;
        transpose_kernel<<<nblk_t, 256, 0, stream>>>(fm, fmtb);
        sample_kernel<<<NBLK_S, 256, 0, stream>>>(fmtb, verts, bary, parents, out);
    } else {
        sample_direct_kernel<<<(TOTAL + 3) / 4, 256, 0, stream>>>(fm, verts, bary, parents, out);
    }
}